// Round 6
// baseline (612.013 us; speedup 1.0000x reference)
//
#include <hip/hip_runtime.h>

// ---------------------------------------------------------------------------
// CausalPD backbone: QKV proj -> fused causal attn + bilinear-bias + L2 norms
// -> out proj.  B=8, L=1024, D=1024, H=16, DK=64.
// All heavy math in bf16 MFMA (16x16x32), fp32 accumulate.
// R6: (A) ln_bilinear restructured: bilT (transposed) + f32x4 row loads +
//     LDS-broadcast c -> ~2x fewer instrs; (B) V GEMM epilogue writes
//     vT directly (k_transpose_v deleted); (C) attn V-LDS rows padded to
//     72 B (18-bank stride, conflict-minimal) fixing the R5 regression.
// ---------------------------------------------------------------------------

typedef __bf16 bf16;
typedef __bf16 bf16x8 __attribute__((ext_vector_type(8)));
typedef __bf16 bf16x4 __attribute__((ext_vector_type(4)));
typedef float  f32x4  __attribute__((ext_vector_type(4)));

#define DEV static __device__ __forceinline__

DEV f32x4 mfma16(bf16x8 a, bf16x8 b, f32x4 c) {
  return __builtin_amdgcn_mfma_f32_16x16x32_bf16(a, b, c, 0, 0, 0);
}

// async global->LDS, 16B per lane (dest = wave-uniform base + lane*16).
DEV void async16(void* lds, const void* g) {
  auto* d = reinterpret_cast<__attribute__((address_space(3))) unsigned int*>(
      (unsigned long long)lds);
  auto* s = reinterpret_cast<const __attribute__((address_space(1))) unsigned int*>(
      (unsigned long long)g);
  __builtin_amdgcn_global_load_lds(s, d, 16, 0, 0);
}

// --------------------------- prep kernels ----------------------------------

__global__ __launch_bounds__(256) void k_cvt(const float* __restrict__ in,
                                             bf16* __restrict__ out, int n4) {
  int i = blockIdx.x * 256 + threadIdx.x;
  if (i >= n4) return;
  f32x4 v = ((const f32x4*)in)[i];
  bf16x4 o = {(bf16)v.x, (bf16)v.y, (bf16)v.z, (bf16)v.w};
  ((bf16x4*)out)[i] = o;
}

// W [1024 k][1024 n] f32  ->  Wt [1024 n][1024 k] bf16
__global__ __launch_bounds__(256) void k_transpose_w(const float* __restrict__ in,
                                                     bf16* __restrict__ out) {
  __shared__ float t[64][65];
  const int k0 = blockIdx.x * 64, n0 = blockIdx.y * 64;
  for (int e = threadIdx.x; e < 4096; e += 256) {
    int r = e >> 6, c = e & 63;
    t[r][c] = in[(size_t)(k0 + r) * 1024 + n0 + c];
  }
  __syncthreads();
  for (int e = threadIdx.x; e < 4096; e += 256) {
    int r = e >> 6, c = e & 63;
    out[(size_t)(n0 + r) * 1024 + k0 + c] = (bf16)t[c][r];
  }
}

// bil [64 in][64 out] f32 -> bilT [64 out][64 in] f32   (one block)
__global__ __launch_bounds__(256) void k_transpose_bil(
    const float* __restrict__ in, float* __restrict__ out) {
  __shared__ float t[64][65];
  for (int e = threadIdx.x; e < 4096; e += 256) t[e >> 6][e & 63] = in[e];
  __syncthreads();
  for (int e = threadIdx.x; e < 4096; e += 256)
    out[e] = t[e & 63][e >> 6];
}

// per (b,l,h): LayerNorm over 64 dims, then cb = c @ bilinear (bilT rows).
__global__ __launch_bounds__(256) void k_ln_bilinear(
    const float* __restrict__ ctx, const float* __restrict__ bilT,
    const float* __restrict__ gam, const float* __restrict__ bet,
    bf16* __restrict__ c_out, bf16* __restrict__ cb_out) {
  __shared__ float cs[4][64];
  const int w = threadIdx.x >> 6, lane = threadIdx.x & 63;
  const int wid = blockIdx.x * 4 + w;        // b*L*H + ... flat
  const int h = wid & 15, bl = wid >> 4;     // bl = b*1024 + l
  const float x = ctx[(size_t)bl * 1024 + h * 64 + lane];
  float s1 = x, s2 = x * x;
#pragma unroll
  for (int m = 32; m >= 1; m >>= 1) {
    s1 += __shfl_xor(s1, m);
    s2 += __shfl_xor(s2, m);
  }
  const float mu = s1 * 0.015625f;
  const float var = s2 * 0.015625f - mu * mu;
  const float cv = (x - mu) * rsqrtf(var + 1e-5f) * gam[lane] + bet[lane];
  const size_t o = ((size_t)((bl >> 10) * 16 + h) * 1024 + (bl & 1023)) * 64 + lane;
  c_out[o] = (bf16)cv;
  cs[w][lane] = cv;
  __syncthreads();
  const f32x4* brow = (const f32x4*)(bilT + (size_t)lane * 64);
  float acc = 0.f;
#pragma unroll
  for (int e4 = 0; e4 < 16; ++e4) {
    const f32x4 b4 = brow[e4];
    const f32x4 c4 = *(const f32x4*)&cs[w][e4 * 4];
    acc += c4.x * b4.x + c4.y * b4.y + c4.z * b4.z + c4.w * b4.w;
  }
  cb_out[o] = (bf16)acc;
}

// --------------------------- GEMM (128x128x32) -----------------------------
// z<2: out bf16 scattered to [B,H,L,DK]; z==2: out bf16 to vT [B,H,DK,L];
// mode==3: out f32 [8192,1024].

struct GemmPtrs {
  const bf16* Bt[3];
  bf16* ob[3];
  const float* bias[3];
};

__global__ __launch_bounds__(256) void k_gemm(const bf16* __restrict__ A,
                                              GemmPtrs p,
                                              float* __restrict__ outf,
                                              int mode) {
  __shared__ __align__(16) bf16 lds[2][2][4096];   // [buf][A/B][128*32]
  const int tid = threadIdx.x;
  const int bm = blockIdx.x, bn = blockIdx.y, z = blockIdx.z;
  const int w = tid >> 6, lane = tid & 63, g = lane >> 4, x = lane & 15;
  const int wr = w >> 1, wc = w & 1;
  const bf16* Bt = p.Bt[z];
  const float* bias = p.bias[z];
  bf16* ob = p.ob[z];

  f32x4 acc[4][4];
#pragma unroll
  for (int mt = 0; mt < 4; ++mt)
#pragma unroll
    for (int nt = 0; nt < 4; ++nt) acc[mt][nt] = f32x4{0.f, 0.f, 0.f, 0.f};

  const bf16* Ab = A + (size_t)bm * 128 * 1024;
  const bf16* Bb = Bt + (size_t)bn * 128 * 1024;

  auto stage = [&](int buf, int t) {
#pragma unroll
    for (int i = 0; i < 2; ++i) {
      int ch = i * 256 + tid;
      int r = ch >> 2, s = ch & 3;
      int sg = (s ^ ((r >> 1) & 3)) * 8;
      async16(&lds[buf][0][ch * 8], Ab + (size_t)r * 1024 + t * 32 + sg);
      async16(&lds[buf][1][ch * 8], Bb + (size_t)r * 1024 + t * 32 + sg);
    }
  };

  stage(0, 0);
  const int sa = (g ^ ((x >> 1) & 3)) * 8;   // swizzled slot for reads
  for (int kt = 0; kt < 32; ++kt) {
    __syncthreads();
    if (kt + 1 < 32) stage((kt + 1) & 1, kt + 1);
    const bf16* la = lds[kt & 1][0];
    const bf16* lb = lds[kt & 1][1];
    bf16x8 af[4], bfr[4];
#pragma unroll
    for (int mt = 0; mt < 4; ++mt)
      af[mt] = *(const bf16x8*)(la + (wr * 64 + mt * 16 + x) * 32 + sa);
#pragma unroll
    for (int nt = 0; nt < 4; ++nt)
      bfr[nt] = *(const bf16x8*)(lb + (wc * 64 + nt * 16 + x) * 32 + sa);
#pragma unroll
    for (int mt = 0; mt < 4; ++mt)
#pragma unroll
      for (int nt = 0; nt < 4; ++nt)
        acc[mt][nt] = mfma16(af[mt], bfr[nt], acc[mt][nt]);
  }

  const int ibase = bm * 128 + wr * 64;
  const int jbase = bn * 128 + wc * 64;
  float bias4[4];
#pragma unroll
  for (int nt = 0; nt < 4; ++nt) bias4[nt] = bias[jbase + nt * 16 + x];

  if (mode < 3) {
    if (z == 2) {
      // V: write transposed [bh][dk][l]; 4 consecutive l -> bf16x4 store.
#pragma unroll
      for (int mt = 0; mt < 4; ++mt)
#pragma unroll
        for (int nt = 0; nt < 4; ++nt) {
          const int jj = jbase + nt * 16 + x;
          const int hh = jj >> 6, dk = jj & 63;
          const int i0 = ibase + mt * 16 + 4 * g;
          const int bb = i0 >> 10, l0 = i0 & 1023;
          bf16x4 v4 = {(bf16)(acc[mt][nt][0] + bias4[nt]),
                       (bf16)(acc[mt][nt][1] + bias4[nt]),
                       (bf16)(acc[mt][nt][2] + bias4[nt]),
                       (bf16)(acc[mt][nt][3] + bias4[nt])};
          *(bf16x4*)&ob[((size_t)(bb * 16 + hh) * 64 + dk) * 1024 + l0] = v4;
        }
    } else {
#pragma unroll
      for (int mt = 0; mt < 4; ++mt)
#pragma unroll
        for (int nt = 0; nt < 4; ++nt) {
          const int jj = jbase + nt * 16 + x;
          const int hh = jj >> 6, dk = jj & 63;
#pragma unroll
          for (int j = 0; j < 4; ++j) {
            const int i = ibase + mt * 16 + 4 * g + j;
            const int bb = i >> 10, l = i & 1023;
            ob[(((size_t)bb * 16 + hh) * 1024 + l) * 64 + dk] =
                (bf16)(acc[mt][nt][j] + bias4[nt]);
          }
        }
    }
  } else {
#pragma unroll
    for (int mt = 0; mt < 4; ++mt)
#pragma unroll
      for (int nt = 0; nt < 4; ++nt) {
        const int jj = jbase + nt * 16 + x;
#pragma unroll
        for (int j = 0; j < 4; ++j) {
          const int i = ibase + mt * 16 + 4 * g + j;
          outf[(size_t)i * 1024 + jj] = acc[mt][nt][j] + bias4[nt];
        }
      }
  }
}

// --------------------------- fused attention -------------------------------
// Per block: one (b,h), 64 q rows (16 per wave). Single pass over k in
// 32-row tiles; fixed-shift softmax (m=0, exact in f32 for |S|<~3);
// streaming Z/E2/Cc/B2 scalars; P round-trips wave-private LDS -> PV.
// K tiles above the causal diagonal neither staged nor multiplied.
// V LDS rows padded to 36 elems (72 B = 18-bank stride: conflict-minimal).
__global__ __launch_bounds__(256, 4) void k_attn(
    const bf16* __restrict__ qg, const bf16* __restrict__ kg,
    const bf16* __restrict__ vTg, const bf16* __restrict__ cg,
    const bf16* __restrict__ cbg, bf16* __restrict__ ao,
    const float* __restrict__ scale_p, const float* __restrict__ bsp) {
  __shared__ __align__(16) bf16 kl[2][2048];     // [k 32][d 64] 8-slot swizzle
  __shared__ __align__(16) bf16 cl[2][2048];     // [k 32][e 64] 8-slot swizzle
  __shared__ __align__(16) bf16 vl[2][64][36];   // [d 64][k 32 pad4] 4-chunk swz
  __shared__ __align__(16) bf16 pe[4][640];      // per-wave [16 q][40]
  __shared__ __align__(16) bf16 pb[4][640];

  const float scl = scale_p[0];
  const float bsc = bsp[0];
  const int tid = threadIdx.x, w = tid >> 6, lane = tid & 63;
  const int g = lane >> 4, x = lane & 15;
  // XCD swizzle: id&7 ~ XCD; per XCD 16 consecutive heads, 16 qtiles inner.
  const int id = blockIdx.x;
  const int xcd = id & 7, sid = id >> 3;       // sid in [0,256)
  const int bh = xcd * 16 + (sid >> 4);        // [0,128)
  const int qt = sid & 15;                     // [0,16)
  const int qrow0 = qt * 64 + w * 16;

  const bf16* qrow = qg + ((size_t)bh * 1024 + qrow0 + x) * 64;
  const bf16* cbrow = cbg + ((size_t)bh * 1024 + qrow0 + x) * 64;
  const bf16x8 qf0 = *(const bf16x8*)(qrow + 8 * g);
  const bf16x8 qf1 = *(const bf16x8*)(qrow + 32 + 8 * g);
  const bf16x8 cbf0 = *(const bf16x8*)(cbrow + 8 * g);
  const bf16x8 cbf1 = *(const bf16x8*)(cbrow + 32 + 8 * g);

  f32x4 acc1[4], acc2[4];
#pragma unroll
  for (int i = 0; i < 4; ++i) {
    acc1[i] = f32x4{0.f, 0.f, 0.f, 0.f};
    acc2[i] = f32x4{0.f, 0.f, 0.f, 0.f};
  }
  float Zs = 0.f, E2 = 0.f, Cc = 0.f, B2 = 0.f;   // fixed-shift softmax state

  const bf16* kbh = kg + (size_t)bh * 65536;
  const bf16* cbh = cg + (size_t)bh * 65536;
  const bf16* vbh = vTg + (size_t)bh * 65536;
  const int nK = 2 * qt + 2;   // 32-row k-tiles needing the K operand

  // stage K,C 32x64 tiles (4 KB each): thread=chunk, r=tid>>3, s=tid&7.
  auto stageKC = [&](int buf, int t) {
    const int r = tid >> 3, s = tid & 7;
    const int sg = (s ^ (r & 7)) * 8;
    if (t < nK)
      async16(&kl[buf][tid * 8], kbh + (size_t)(t * 32 + r) * 64 + sg);
    async16(&cl[buf][tid * 8], cbh + (size_t)(t * 32 + r) * 64 + sg);
  };
  // V tile 64x32: reg-staged (padded LDS rows break global_load_lds).
  bf16x8 vreg;
  auto loadV = [&](int t) {
    const int r = tid >> 2, s = tid & 3;
    vreg = *(const bf16x8*)(vbh + (size_t)r * 1024 + t * 32 + s * 8);
  };
  auto writeV = [&](int buf) {
    const int r = tid >> 2, s = tid & 3;
    *(bf16x8*)&vl[buf][r][(s ^ (r & 3)) * 8] = vreg;
  };

  stageKC(0, 0);
  loadV(0);
  writeV(0);
  for (int t = 0; t < 32; ++t) {
    __syncthreads();
    if (t + 1 < 32) {
      stageKC((t + 1) & 1, t + 1);
      loadV(t + 1);
    }
    const bf16* klb = kl[t & 1];
    const bf16* clb = cl[t & 1];
    const int tileK = t * 32;
    const bool hv = tileK <= qrow0 + 15;   // any softmax-valid k in tile
    float sv[8], bv[8];
#pragma unroll
    for (int sub = 0; sub < 2; ++sub) {
      const int rloc = sub * 16 + x;
      const int so0 = (g ^ (rloc & 7)) * 8;
      const int so1 = ((4 + g) ^ (rloc & 7)) * 8;
      const bf16* cr = clb + rloc * 64;
      f32x4 bacc = f32x4{0.f, 0.f, 0.f, 0.f};
      bacc = mfma16(*(const bf16x8*)(cr + so0), cbf0, bacc);
      bacc = mfma16(*(const bf16x8*)(cr + so1), cbf1, bacc);
      const int k16 = tileK + sub * 16;
      const bool av = k16 <= qrow0 + 15;
      const bool full = (k16 + 15) <= qrow0;   // whole subtile unmasked
      f32x4 sacc = f32x4{0.f, 0.f, 0.f, 0.f};
      if (av) {
        const bf16* kr = klb + rloc * 64;
        sacc = mfma16(*(const bf16x8*)(kr + so0), qf0, sacc);
        sacc = mfma16(*(const bf16x8*)(kr + so1), qf1, sacc);
      }
      const int q = qrow0 + x;
#pragma unroll
      for (int j = 0; j < 4; ++j) {
        bv[sub * 4 + j] = bacc[j];
        B2 += bacc[j] * bacc[j];
        const int kk = k16 + 4 * g + j;
        sv[sub * 4 + j] =
            full ? sacc[j] * scl
                 : ((av && kk <= q) ? sacc[j] * scl : -1e30f);
      }
    }
    if (hv) {
      float ev[8];
#pragma unroll
      for (int jj = 0; jj < 8; ++jj) {
        const float e = __expf(sv[jj]);      // exp(-1e30) flushes to 0
        ev[jj] = e;
        Zs += e; E2 += e * e; Cc += e * bv[jj];
      }
      bf16x4 e0 = {(bf16)ev[0], (bf16)ev[1], (bf16)ev[2], (bf16)ev[3]};
      bf16x4 e1 = {(bf16)ev[4], (bf16)ev[5], (bf16)ev[6], (bf16)ev[7]};
      *(bf16x4*)&pe[w][x * 40 + 4 * g] = e0;
      *(bf16x4*)&pe[w][x * 40 + 16 + 4 * g] = e1;
    }
    bf16x4 b0 = {(bf16)bv[0], (bf16)bv[1], (bf16)bv[2], (bf16)bv[3]};
    bf16x4 b1 = {(bf16)bv[4], (bf16)bv[5], (bf16)bv[6], (bf16)bv[7]};
    *(bf16x4*)&pb[w][x * 40 + 4 * g] = b0;
    *(bf16x4*)&pb[w][x * 40 + 16 + 4 * g] = b1;
    // PV over this 32-k tile
    const bf16x8 pbf = *(const bf16x8*)&pb[w][x * 40 + 8 * g];
#pragma unroll
    for (int nt = 0; nt < 4; ++nt) {
      const int dr = nt * 16 + x;
      const bf16x8 vf = *(const bf16x8*)&vl[t & 1][dr][(g ^ (dr & 3)) * 8];
      acc2[nt] = mfma16(pbf, vf, acc2[nt]);
    }
    if (hv) {
      const bf16x8 pef = *(const bf16x8*)&pe[w][x * 40 + 8 * g];
#pragma unroll
      for (int nt = 0; nt < 4; ++nt) {
        const int dr = nt * 16 + x;
        const bf16x8 vf = *(const bf16x8*)&vl[t & 1][dr][(g ^ (dr & 3)) * 8];
        acc1[nt] = mfma16(pef, vf, acc1[nt]);
      }
    }
    if (t + 1 < 32) writeV((t + 1) & 1);
  }

  // reduce partial scalars across the 4 lane-groups
  Zs += __shfl_xor(Zs, 16); Zs += __shfl_xor(Zs, 32);
  E2 += __shfl_xor(E2, 16); E2 += __shfl_xor(E2, 32);
  Cc += __shfl_xor(Cc, 16); Cc += __shfl_xor(Cc, 32);
  B2 += __shfl_xor(B2, 16); B2 += __shfl_xor(B2, 32);
  const float bnorm = fmaxf(sqrtf(B2), 1e-12f);
  const float invZ = 1.0f / Zs;
  const float n2 = E2 * invZ * invZ + 2.0f * bsc * Cc * invZ / bnorm +
                   bsc * bsc * B2 / (bnorm * bnorm);
  const float inv_an = 1.0f / fmaxf(sqrtf(n2), 1e-12f);
  const float cA = invZ * inv_an;
  const float cB = bsc / bnorm * inv_an;
  const int b_ = bh >> 4, h_ = bh & 15;
#pragma unroll
  for (int j = 0; j < 4; ++j) {
    const int src = (lane & 48) | (4 * g + j);
    const float cAj = __shfl(cA, src);
    const float cBj = __shfl(cB, src);
    const int qr = qrow0 + 4 * g + j;
#pragma unroll
    for (int nt = 0; nt < 4; ++nt) {
      const float o = cAj * acc1[nt][j] + cBj * acc2[nt][j];
      ao[(size_t)(b_ * 1024 + qr) * 1024 + h_ * 64 + nt * 16 + x] = (bf16)o;
    }
  }
}

// --------------------------- launcher --------------------------------------

extern "C" void kernel_launch(void* const* d_in, const int* in_sizes, int n_in,
                              void* d_out, int out_size, void* d_ws,
                              size_t ws_size, hipStream_t stream) {
  const float* Q   = (const float*)d_in[0];
  const float* ctx = (const float*)d_in[1];
  // d_in[2] = attn_mask (causal triu) — implemented analytically.
  const float* Wq  = (const float*)d_in[3];
  const float* bq  = (const float*)d_in[4];
  const float* Wk  = (const float*)d_in[5];
  const float* bk  = (const float*)d_in[6];
  const float* Wv  = (const float*)d_in[7];
  const float* bvp = (const float*)d_in[8];
  const float* bil = (const float*)d_in[9];
  const float* gam = (const float*)d_in[10];
  const float* bet = (const float*)d_in[11];
  const float* scl = (const float*)d_in[12];
  const float* bsc = (const float*)d_in[13];
  const float* Wo  = (const float*)d_in[14];
  const float* bo  = (const float*)d_in[15];
  float* out = (float*)d_out;
  char* ws = (char*)d_ws;
  const size_t MB = 1ull << 20;

  bf16* Qb  = (bf16*)(ws + 0);        // 16 MB (reused as ao after QKV GEMM)
  bf16* Wtq = (bf16*)(ws + 16 * MB);  // 2 MB each
  bf16* Wtk = (bf16*)(ws + 18 * MB);
  bf16* Wtv = (bf16*)(ws + 20 * MB);
  bf16* Wto = (bf16*)(ws + 22 * MB);
  bf16* qb  = (bf16*)(ws + 24 * MB);  // 16 MB [B,H,L,DK]
  bf16* kb  = (bf16*)(ws + 40 * MB);
  bf16* vT  = (bf16*)(ws + 72 * MB);  // [B,H,DK,L] (written by GEMM z=2)
  bf16* cN  = (bf16*)(ws + 88 * MB);
  bf16* cbN = (bf16*)(ws + 104 * MB);
  float* bilT = (float*)(ws + 120 * MB);  // 16 KB
  bf16* ao  = Qb;                     // alias: Qb dead after QKV GEMM

  k_cvt<<<8192, 256, 0, stream>>>(Q, Qb, 2097152);
  k_transpose_w<<<dim3(16, 16), 256, 0, stream>>>(Wq, Wtq);
  k_transpose_w<<<dim3(16, 16), 256, 0, stream>>>(Wk, Wtk);
  k_transpose_w<<<dim3(16, 16), 256, 0, stream>>>(Wv, Wtv);
  k_transpose_w<<<dim3(16, 16), 256, 0, stream>>>(Wo, Wto);
  k_transpose_bil<<<1, 256, 0, stream>>>(bil, bilT);
  k_ln_bilinear<<<32768, 256, 0, stream>>>(ctx, bilT, gam, bet, cN, cbN);

  GemmPtrs p1{{Wtq, Wtk, Wtv}, {qb, kb, vT}, {bq, bk, bvp}};
  k_gemm<<<dim3(64, 8, 3), 256, 0, stream>>>(Qb, p1, nullptr, 0);

  k_attn<<<2048, 256, 0, stream>>>(qb, kb, vT, cN, cbN, ao, scl, bsc);

  GemmPtrs p2{{Wto, Wto, Wto}, {nullptr, nullptr, nullptr}, {bo, bo, bo}};
  k_gemm<<<dim3(64, 8, 1), 256, 0, stream>>>(ao, p2, out, 3);

  (void)in_sizes; (void)n_in; (void)out_size; (void)ws_size;
}

// Round 8
// 411.588 us; speedup vs baseline: 1.4870x; 1.4870x over previous
//
#include <hip/hip_runtime.h>

// ---------------------------------------------------------------------------
// CausalPD backbone: QKV proj -> fused causal attn + bilinear-bias + L2 norms
// -> out proj.  B=8, L=1024, D=1024, H=16, DK=64.
// All heavy math in bf16 MFMA (16x16x32), fp32 accumulate.
// R7 (resubmitted in R8 after GPU-acquisition timeout): ln_bilinear rebuilt
//     register-resident: bil held in 64 VGPRs per wave (loaded once,
//     coalesced), inner loop = readlane broadcast + fmac only.  R6's
//     bilT/f32x4 path (uncoalesced 256B-stride lane reads, 243 us) and its
//     transpose kernel deleted.  Attn + GEMM unchanged from R6.
// ---------------------------------------------------------------------------

typedef __bf16 bf16;
typedef __bf16 bf16x8 __attribute__((ext_vector_type(8)));
typedef __bf16 bf16x4 __attribute__((ext_vector_type(4)));
typedef float  f32x4  __attribute__((ext_vector_type(4)));

#define DEV static __device__ __forceinline__

DEV f32x4 mfma16(bf16x8 a, bf16x8 b, f32x4 c) {
  return __builtin_amdgcn_mfma_f32_16x16x32_bf16(a, b, c, 0, 0, 0);
}

// async global->LDS, 16B per lane (dest = wave-uniform base + lane*16).
DEV void async16(void* lds, const void* g) {
  auto* d = reinterpret_cast<__attribute__((address_space(3))) unsigned int*>(
      (unsigned long long)lds);
  auto* s = reinterpret_cast<const __attribute__((address_space(1))) unsigned int*>(
      (unsigned long long)g);
  __builtin_amdgcn_global_load_lds(s, d, 16, 0, 0);
}

// --------------------------- prep kernels ----------------------------------

__global__ __launch_bounds__(256) void k_cvt(const float* __restrict__ in,
                                             bf16* __restrict__ out, int n4) {
  int i = blockIdx.x * 256 + threadIdx.x;
  if (i >= n4) return;
  f32x4 v = ((const f32x4*)in)[i];
  bf16x4 o = {(bf16)v.x, (bf16)v.y, (bf16)v.z, (bf16)v.w};
  ((bf16x4*)out)[i] = o;
}

// W [1024 k][1024 n] f32  ->  Wt [1024 n][1024 k] bf16
__global__ __launch_bounds__(256) void k_transpose_w(const float* __restrict__ in,
                                                     bf16* __restrict__ out) {
  __shared__ float t[64][65];
  const int k0 = blockIdx.x * 64, n0 = blockIdx.y * 64;
  for (int e = threadIdx.x; e < 4096; e += 256) {
    int r = e >> 6, c = e & 63;
    t[r][c] = in[(size_t)(k0 + r) * 1024 + n0 + c];
  }
  __syncthreads();
  for (int e = threadIdx.x; e < 4096; e += 256) {
    int r = e >> 6, c = e & 63;
    out[(size_t)(n0 + r) * 1024 + k0 + c] = (bf16)t[c][r];
  }
}

// per (b,l,h): LayerNorm over 64 dims, then cb = c @ bilinear.
// bil kept register-resident per wave: bilreg[e] = bil[e][lane] (64 VGPRs,
// loaded once, lane-coalesced).  Inner loop: readlane(c[e]) bcast + fmac.
__global__ __launch_bounds__(256, 4) void k_ln_bilinear(
    const float* __restrict__ ctx, const float* __restrict__ bil,
    const float* __restrict__ gam, const float* __restrict__ bet,
    bf16* __restrict__ c_out, bf16* __restrict__ cb_out) {
  const int w = threadIdx.x >> 6, lane = threadIdx.x & 63;
  float bilreg[64];
#pragma unroll
  for (int e = 0; e < 64; ++e) bilreg[e] = bil[e * 64 + lane];
  const float gm = gam[lane], bt = bet[lane];
  const int wid = blockIdx.x * 4 + w;          // [0, 8192)
  for (int it = 0; it < 16; ++it) {
    const int row = wid * 16 + it;             // = bl*16 + h
    const int h = row & 15, bl = row >> 4;
    const float x = ctx[(size_t)row * 64 + lane];
    float s1 = x, s2 = x * x;
#pragma unroll
    for (int mm = 32; mm >= 1; mm >>= 1) {
      s1 += __shfl_xor(s1, mm);
      s2 += __shfl_xor(s2, mm);
    }
    const float mu = s1 * 0.015625f;
    const float var = s2 * 0.015625f - mu * mu;
    const float cv = (x - mu) * rsqrtf(var + 1e-5f) * gm + bt;
    float a0 = 0.f, a1 = 0.f, a2 = 0.f, a3 = 0.f;
#pragma unroll
    for (int e = 0; e < 64; e += 4) {
      a0 += __int_as_float(__builtin_amdgcn_readlane(__float_as_int(cv), e + 0)) * bilreg[e + 0];
      a1 += __int_as_float(__builtin_amdgcn_readlane(__float_as_int(cv), e + 1)) * bilreg[e + 1];
      a2 += __int_as_float(__builtin_amdgcn_readlane(__float_as_int(cv), e + 2)) * bilreg[e + 2];
      a3 += __int_as_float(__builtin_amdgcn_readlane(__float_as_int(cv), e + 3)) * bilreg[e + 3];
    }
    const float acc = (a0 + a1) + (a2 + a3);
    const size_t o =
        ((size_t)((bl >> 10) * 16 + h) * 1024 + (bl & 1023)) * 64 + lane;
    c_out[o] = (bf16)cv;
    cb_out[o] = (bf16)acc;
  }
}

// --------------------------- GEMM (128x128x32) -----------------------------
// z<2: out bf16 scattered to [B,H,L,DK]; z==2: out bf16 to vT [B,H,DK,L];
// mode==3: out f32 [8192,1024].

struct GemmPtrs {
  const bf16* Bt[3];
  bf16* ob[3];
  const float* bias[3];
};

__global__ __launch_bounds__(256) void k_gemm(const bf16* __restrict__ A,
                                              GemmPtrs p,
                                              float* __restrict__ outf,
                                              int mode) {
  __shared__ __align__(16) bf16 lds[2][2][4096];   // [buf][A/B][128*32]
  const int tid = threadIdx.x;
  const int bm = blockIdx.x, bn = blockIdx.y, z = blockIdx.z;
  const int w = tid >> 6, lane = tid & 63, g = lane >> 4, x = lane & 15;
  const int wr = w >> 1, wc = w & 1;
  const bf16* Bt = p.Bt[z];
  const float* bias = p.bias[z];
  bf16* ob = p.ob[z];

  f32x4 acc[4][4];
#pragma unroll
  for (int mt = 0; mt < 4; ++mt)
#pragma unroll
    for (int nt = 0; nt < 4; ++nt) acc[mt][nt] = f32x4{0.f, 0.f, 0.f, 0.f};

  const bf16* Ab = A + (size_t)bm * 128 * 1024;
  const bf16* Bb = Bt + (size_t)bn * 128 * 1024;

  auto stage = [&](int buf, int t) {
#pragma unroll
    for (int i = 0; i < 2; ++i) {
      int ch = i * 256 + tid;
      int r = ch >> 2, s = ch & 3;
      int sg = (s ^ ((r >> 1) & 3)) * 8;
      async16(&lds[buf][0][ch * 8], Ab + (size_t)r * 1024 + t * 32 + sg);
      async16(&lds[buf][1][ch * 8], Bb + (size_t)r * 1024 + t * 32 + sg);
    }
  };

  stage(0, 0);
  const int sa = (g ^ ((x >> 1) & 3)) * 8;   // swizzled slot for reads
  for (int kt = 0; kt < 32; ++kt) {
    __syncthreads();
    if (kt + 1 < 32) stage((kt + 1) & 1, kt + 1);
    const bf16* la = lds[kt & 1][0];
    const bf16* lb = lds[kt & 1][1];
    bf16x8 af[4], bfr[4];
#pragma unroll
    for (int mt = 0; mt < 4; ++mt)
      af[mt] = *(const bf16x8*)(la + (wr * 64 + mt * 16 + x) * 32 + sa);
#pragma unroll
    for (int nt = 0; nt < 4; ++nt)
      bfr[nt] = *(const bf16x8*)(lb + (wc * 64 + nt * 16 + x) * 32 + sa);
#pragma unroll
    for (int mt = 0; mt < 4; ++mt)
#pragma unroll
      for (int nt = 0; nt < 4; ++nt)
        acc[mt][nt] = mfma16(af[mt], bfr[nt], acc[mt][nt]);
  }

  const int ibase = bm * 128 + wr * 64;
  const int jbase = bn * 128 + wc * 64;
  float bias4[4];
#pragma unroll
  for (int nt = 0; nt < 4; ++nt) bias4[nt] = bias[jbase + nt * 16 + x];

  if (mode < 3) {
    if (z == 2) {
      // V: write transposed [bh][dk][l]; 4 consecutive l -> bf16x4 store.
#pragma unroll
      for (int mt = 0; mt < 4; ++mt)
#pragma unroll
        for (int nt = 0; nt < 4; ++nt) {
          const int jj = jbase + nt * 16 + x;
          const int hh = jj >> 6, dk = jj & 63;
          const int i0 = ibase + mt * 16 + 4 * g;
          const int bb = i0 >> 10, l0 = i0 & 1023;
          bf16x4 v4 = {(bf16)(acc[mt][nt][0] + bias4[nt]),
                       (bf16)(acc[mt][nt][1] + bias4[nt]),
                       (bf16)(acc[mt][nt][2] + bias4[nt]),
                       (bf16)(acc[mt][nt][3] + bias4[nt])};
          *(bf16x4*)&ob[((size_t)(bb * 16 + hh) * 64 + dk) * 1024 + l0] = v4;
        }
    } else {
#pragma unroll
      for (int mt = 0; mt < 4; ++mt)
#pragma unroll
        for (int nt = 0; nt < 4; ++nt) {
          const int jj = jbase + nt * 16 + x;
          const int hh = jj >> 6, dk = jj & 63;
#pragma unroll
          for (int j = 0; j < 4; ++j) {
            const int i = ibase + mt * 16 + 4 * g + j;
            const int bb = i >> 10, l = i & 1023;
            ob[(((size_t)bb * 16 + hh) * 1024 + l) * 64 + dk] =
                (bf16)(acc[mt][nt][j] + bias4[nt]);
          }
        }
    }
  } else {
#pragma unroll
    for (int mt = 0; mt < 4; ++mt)
#pragma unroll
      for (int nt = 0; nt < 4; ++nt) {
        const int jj = jbase + nt * 16 + x;
#pragma unroll
        for (int j = 0; j < 4; ++j) {
          const int i = ibase + mt * 16 + 4 * g + j;
          outf[(size_t)i * 1024 + jj] = acc[mt][nt][j] + bias4[nt];
        }
      }
  }
}

// --------------------------- fused attention -------------------------------
// Per block: one (b,h), 64 q rows (16 per wave). Single pass over k in
// 32-row tiles; fixed-shift softmax (m=0, exact in f32 for |S|<~3);
// streaming Z/E2/Cc/B2 scalars; P round-trips wave-private LDS -> PV.
// K tiles above the causal diagonal neither staged nor multiplied.
// V LDS rows padded to 36 elems (72 B = 18-bank stride: conflict-minimal).
__global__ __launch_bounds__(256, 4) void k_attn(
    const bf16* __restrict__ qg, const bf16* __restrict__ kg,
    const bf16* __restrict__ vTg, const bf16* __restrict__ cg,
    const bf16* __restrict__ cbg, bf16* __restrict__ ao,
    const float* __restrict__ scale_p, const float* __restrict__ bsp) {
  __shared__ __align__(16) bf16 kl[2][2048];     // [k 32][d 64] 8-slot swizzle
  __shared__ __align__(16) bf16 cl[2][2048];     // [k 32][e 64] 8-slot swizzle
  __shared__ __align__(16) bf16 vl[2][64][36];   // [d 64][k 32 pad4] 4-chunk swz
  __shared__ __align__(16) bf16 pe[4][640];      // per-wave [16 q][40]
  __shared__ __align__(16) bf16 pb[4][640];

  const float scl = scale_p[0];
  const float bsc = bsp[0];
  const int tid = threadIdx.x, w = tid >> 6, lane = tid & 63;
  const int g = lane >> 4, x = lane & 15;
  // XCD swizzle: id&7 ~ XCD; per XCD 16 consecutive heads, 16 qtiles inner.
  const int id = blockIdx.x;
  const int xcd = id & 7, sid = id >> 3;       // sid in [0,256)
  const int bh = xcd * 16 + (sid >> 4);        // [0,128)
  const int qt = sid & 15;                     // [0,16)
  const int qrow0 = qt * 64 + w * 16;

  const bf16* qrow = qg + ((size_t)bh * 1024 + qrow0 + x) * 64;
  const bf16* cbrow = cbg + ((size_t)bh * 1024 + qrow0 + x) * 64;
  const bf16x8 qf0 = *(const bf16x8*)(qrow + 8 * g);
  const bf16x8 qf1 = *(const bf16x8*)(qrow + 32 + 8 * g);
  const bf16x8 cbf0 = *(const bf16x8*)(cbrow + 8 * g);
  const bf16x8 cbf1 = *(const bf16x8*)(cbrow + 32 + 8 * g);

  f32x4 acc1[4], acc2[4];
#pragma unroll
  for (int i = 0; i < 4; ++i) {
    acc1[i] = f32x4{0.f, 0.f, 0.f, 0.f};
    acc2[i] = f32x4{0.f, 0.f, 0.f, 0.f};
  }
  float Zs = 0.f, E2 = 0.f, Cc = 0.f, B2 = 0.f;   // fixed-shift softmax state

  const bf16* kbh = kg + (size_t)bh * 65536;
  const bf16* cbh = cg + (size_t)bh * 65536;
  const bf16* vbh = vTg + (size_t)bh * 65536;
  const int nK = 2 * qt + 2;   // 32-row k-tiles needing the K operand

  // stage K,C 32x64 tiles (4 KB each): thread=chunk, r=tid>>3, s=tid&7.
  auto stageKC = [&](int buf, int t) {
    const int r = tid >> 3, s = tid & 7;
    const int sg = (s ^ (r & 7)) * 8;
    if (t < nK)
      async16(&kl[buf][tid * 8], kbh + (size_t)(t * 32 + r) * 64 + sg);
    async16(&cl[buf][tid * 8], cbh + (size_t)(t * 32 + r) * 64 + sg);
  };
  // V tile 64x32: reg-staged (padded LDS rows break global_load_lds).
  bf16x8 vreg;
  auto loadV = [&](int t) {
    const int r = tid >> 2, s = tid & 3;
    vreg = *(const bf16x8*)(vbh + (size_t)r * 1024 + t * 32 + s * 8);
  };
  auto writeV = [&](int buf) {
    const int r = tid >> 2, s = tid & 3;
    *(bf16x8*)&vl[buf][r][(s ^ (r & 3)) * 8] = vreg;
  };

  stageKC(0, 0);
  loadV(0);
  writeV(0);
  for (int t = 0; t < 32; ++t) {
    __syncthreads();
    if (t + 1 < 32) {
      stageKC((t + 1) & 1, t + 1);
      loadV(t + 1);
    }
    const bf16* klb = kl[t & 1];
    const bf16* clb = cl[t & 1];
    const int tileK = t * 32;
    const bool hv = tileK <= qrow0 + 15;   // any softmax-valid k in tile
    float sv[8], bv[8];
#pragma unroll
    for (int sub = 0; sub < 2; ++sub) {
      const int rloc = sub * 16 + x;
      const int so0 = (g ^ (rloc & 7)) * 8;
      const int so1 = ((4 + g) ^ (rloc & 7)) * 8;
      const bf16* cr = clb + rloc * 64;
      f32x4 bacc = f32x4{0.f, 0.f, 0.f, 0.f};
      bacc = mfma16(*(const bf16x8*)(cr + so0), cbf0, bacc);
      bacc = mfma16(*(const bf16x8*)(cr + so1), cbf1, bacc);
      const int k16 = tileK + sub * 16;
      const bool av = k16 <= qrow0 + 15;
      const bool full = (k16 + 15) <= qrow0;   // whole subtile unmasked
      f32x4 sacc = f32x4{0.f, 0.f, 0.f, 0.f};
      if (av) {
        const bf16* kr = klb + rloc * 64;
        sacc = mfma16(*(const bf16x8*)(kr + so0), qf0, sacc);
        sacc = mfma16(*(const bf16x8*)(kr + so1), qf1, sacc);
      }
      const int q = qrow0 + x;
#pragma unroll
      for (int j = 0; j < 4; ++j) {
        bv[sub * 4 + j] = bacc[j];
        B2 += bacc[j] * bacc[j];
        const int kk = k16 + 4 * g + j;
        sv[sub * 4 + j] =
            full ? sacc[j] * scl
                 : ((av && kk <= q) ? sacc[j] * scl : -1e30f);
      }
    }
    if (hv) {
      float ev[8];
#pragma unroll
      for (int jj = 0; jj < 8; ++jj) {
        const float e = __expf(sv[jj]);      // exp(-1e30) flushes to 0
        ev[jj] = e;
        Zs += e; E2 += e * e; Cc += e * bv[jj];
      }
      bf16x4 e0 = {(bf16)ev[0], (bf16)ev[1], (bf16)ev[2], (bf16)ev[3]};
      bf16x4 e1 = {(bf16)ev[4], (bf16)ev[5], (bf16)ev[6], (bf16)ev[7]};
      *(bf16x4*)&pe[w][x * 40 + 4 * g] = e0;
      *(bf16x4*)&pe[w][x * 40 + 16 + 4 * g] = e1;
    }
    bf16x4 b0 = {(bf16)bv[0], (bf16)bv[1], (bf16)bv[2], (bf16)bv[3]};
    bf16x4 b1 = {(bf16)bv[4], (bf16)bv[5], (bf16)bv[6], (bf16)bv[7]};
    *(bf16x4*)&pb[w][x * 40 + 4 * g] = b0;
    *(bf16x4*)&pb[w][x * 40 + 16 + 4 * g] = b1;
    // PV over this 32-k tile
    const bf16x8 pbf = *(const bf16x8*)&pb[w][x * 40 + 8 * g];
#pragma unroll
    for (int nt = 0; nt < 4; ++nt) {
      const int dr = nt * 16 + x;
      const bf16x8 vf = *(const bf16x8*)&vl[t & 1][dr][(g ^ (dr & 3)) * 8];
      acc2[nt] = mfma16(pbf, vf, acc2[nt]);
    }
    if (hv) {
      const bf16x8 pef = *(const bf16x8*)&pe[w][x * 40 + 8 * g];
#pragma unroll
      for (int nt = 0; nt < 4; ++nt) {
        const int dr = nt * 16 + x;
        const bf16x8 vf = *(const bf16x8*)&vl[t & 1][dr][(g ^ (dr & 3)) * 8];
        acc1[nt] = mfma16(pef, vf, acc1[nt]);
      }
    }
    if (t + 1 < 32) writeV((t + 1) & 1);
  }

  // reduce partial scalars across the 4 lane-groups
  Zs += __shfl_xor(Zs, 16); Zs += __shfl_xor(Zs, 32);
  E2 += __shfl_xor(E2, 16); E2 += __shfl_xor(E2, 32);
  Cc += __shfl_xor(Cc, 16); Cc += __shfl_xor(Cc, 32);
  B2 += __shfl_xor(B2, 16); B2 += __shfl_xor(B2, 32);
  const float bnorm = fmaxf(sqrtf(B2), 1e-12f);
  const float invZ = 1.0f / Zs;
  const float n2 = E2 * invZ * invZ + 2.0f * bsc * Cc * invZ / bnorm +
                   bsc * bsc * B2 / (bnorm * bnorm);
  const float inv_an = 1.0f / fmaxf(sqrtf(n2), 1e-12f);
  const float cA = invZ * inv_an;
  const float cB = bsc / bnorm * inv_an;
  const int b_ = bh >> 4, h_ = bh & 15;
#pragma unroll
  for (int j = 0; j < 4; ++j) {
    const int src = (lane & 48) | (4 * g + j);
    const float cAj = __shfl(cA, src);
    const float cBj = __shfl(cB, src);
    const int qr = qrow0 + 4 * g + j;
#pragma unroll
    for (int nt = 0; nt < 4; ++nt) {
      const float o = cAj * acc1[nt][j] + cBj * acc2[nt][j];
      ao[(size_t)(b_ * 1024 + qr) * 1024 + h_ * 64 + nt * 16 + x] = (bf16)o;
    }
  }
}

// --------------------------- launcher --------------------------------------

extern "C" void kernel_launch(void* const* d_in, const int* in_sizes, int n_in,
                              void* d_out, int out_size, void* d_ws,
                              size_t ws_size, hipStream_t stream) {
  const float* Q   = (const float*)d_in[0];
  const float* ctx = (const float*)d_in[1];
  // d_in[2] = attn_mask (causal triu) — implemented analytically.
  const float* Wq  = (const float*)d_in[3];
  const float* bq  = (const float*)d_in[4];
  const float* Wk  = (const float*)d_in[5];
  const float* bk  = (const float*)d_in[6];
  const float* Wv  = (const float*)d_in[7];
  const float* bvp = (const float*)d_in[8];
  const float* bil = (const float*)d_in[9];
  const float* gam = (const float*)d_in[10];
  const float* bet = (const float*)d_in[11];
  const float* scl = (const float*)d_in[12];
  const float* bsc = (const float*)d_in[13];
  const float* Wo  = (const float*)d_in[14];
  const float* bo  = (const float*)d_in[15];
  float* out = (float*)d_out;
  char* ws = (char*)d_ws;
  const size_t MB = 1ull << 20;

  bf16* Qb  = (bf16*)(ws + 0);        // 16 MB (reused as ao after QKV GEMM)
  bf16* Wtq = (bf16*)(ws + 16 * MB);  // 2 MB each
  bf16* Wtk = (bf16*)(ws + 18 * MB);
  bf16* Wtv = (bf16*)(ws + 20 * MB);
  bf16* Wto = (bf16*)(ws + 22 * MB);
  bf16* qb  = (bf16*)(ws + 24 * MB);  // 16 MB [B,H,L,DK]
  bf16* kb  = (bf16*)(ws + 40 * MB);
  bf16* vT  = (bf16*)(ws + 72 * MB);  // [B,H,DK,L] (written by GEMM z=2)
  bf16* cN  = (bf16*)(ws + 88 * MB);
  bf16* cbN = (bf16*)(ws + 104 * MB);
  bf16* ao  = Qb;                     // alias: Qb dead after QKV GEMM

  k_cvt<<<8192, 256, 0, stream>>>(Q, Qb, 2097152);
  k_transpose_w<<<dim3(16, 16), 256, 0, stream>>>(Wq, Wtq);
  k_transpose_w<<<dim3(16, 16), 256, 0, stream>>>(Wk, Wtk);
  k_transpose_w<<<dim3(16, 16), 256, 0, stream>>>(Wv, Wtv);
  k_transpose_w<<<dim3(16, 16), 256, 0, stream>>>(Wo, Wto);
  k_ln_bilinear<<<2048, 256, 0, stream>>>(ctx, bil, gam, bet, cN, cbN);

  GemmPtrs p1{{Wtq, Wtk, Wtv}, {qb, kb, vT}, {bq, bk, bvp}};
  k_gemm<<<dim3(64, 8, 3), 256, 0, stream>>>(Qb, p1, nullptr, 0);

  k_attn<<<2048, 256, 0, stream>>>(qb, kb, vT, cN, cbN, ao, scl, bsc);

  GemmPtrs p2{{Wto, Wto, Wto}, {nullptr, nullptr, nullptr}, {bo, bo, bo}};
  k_gemm<<<dim3(64, 8, 1), 256, 0, stream>>>(ao, p2, out, 3);

  (void)in_sizes; (void)n_in; (void)out_size; (void)ws_size;
}